// Round 5
// baseline (535.908 us; speedup 1.0000x reference)
//
#include <hip/hip_runtime.h>
#include <hip/hip_bf16.h>

// Fused 2-layer LSTM (H=32) + linear head, MI355X gfx950.
// Wave-specialized + layer-pipelined: 256 WGs x 8 waves, 16 batch rows/WG.
// Per (layer, unit-half): wave A = input-side MFMAs (x@Wih or h1@Wih1),
// wave B = recurrent-side (h@Whh). A/B exchange half their partial C-frags
// via LDS (lane-aligned, no transpose), then each finishes 2 cells/lane.
// L1 runs step s while L2 runs step s-1. Two lgkm-only barriers per step.
// 2048 useful waves = 2 waves/SIMD. Hi/lo bf16 split (~fp32 exact).

#define T_LEN 512
#define D_IN  28

typedef __attribute__((ext_vector_type(8))) short short8;  // 8 x bf16
typedef __attribute__((ext_vector_type(4))) float f32x4;

#define K_SIG 1.4426950408889634f   // 1/ln2
#define K_TANH 2.8853900817779268f  // 2/ln2

// hi = bf16 truncation of x, lo = bf16 of exact residual (x - hi).
__device__ __forceinline__ void split_bf16(float x, short& hi, short& lo) {
  unsigned u = __float_as_uint(x);
  hi = (short)(u >> 16);
  float hf_ = __uint_as_float(u & 0xFFFF0000u);
  float lf = x - hf_;  // exact
  lo = (short)(__float_as_uint(lf) >> 16);
}

// Barrier that drains LDS ops only (x prefetch stays in flight).
__device__ __forceinline__ void lds_barrier() {
  asm volatile("s_waitcnt lgkmcnt(0)\n\ts_barrier" ::: "memory");
}

// B-operand tile (K=32 x N=16) of W (row-major G x ldk), gate rows
// n*16..n*16+15, k zero-padded past kval. Lane l: col=l&15, k=(l>>4)*8..+8.
__device__ __forceinline__ void load_wtile(const float* __restrict__ W, int ldk,
                                           int kval, int n, int lane,
                                           short8& hi, short8& lo) {
  int row = n * 16 + (lane & 15);
  int kb = (lane >> 4) * 8;
  const float* p = W + row * ldk + kb;
#pragma unroll
  for (int i = 0; i < 8; ++i) {
    float v = (kb + i < kval) ? p[i] : 0.0f;
    short h, l;
    split_bf16(v, h, l);
    hi[i] = h; lo[i] = l;
  }
}

#define MFMA(a, b, c) __builtin_amdgcn_mfma_f32_16x16x32_bf16(a, b, c, 0, 0, 0)

__global__ __launch_bounds__(512) void lstm2_ws(
    const float* __restrict__ x, const float* __restrict__ wih0,
    const float* __restrict__ whh0, const float* __restrict__ wih1,
    const float* __restrict__ whh1, const float* __restrict__ wout,
    const float* __restrict__ bout, float* __restrict__ out) {
  __shared__ short h1buf[2][2][16][40];  // [parity][hi/lo][row][unit pad 40]
  __shared__ short h2buf[2][2][16][40];
  __shared__ float xch[2][2][2][64][8];  // [layer][uhalf][role][lane][tt*2+j]
  __shared__ float hf[16][33];

  const int tid = threadIdx.x;
  const int lane = tid & 63;
  const int wid = tid >> 6;      // 0..7
  const int layer = wid >> 2;    // 0: L1 waves, 1: L2 waves
  const int roleB = (wid >> 1) & 1;  // 0 = A (input side), 1 = B (recurrent)
  const int uhalf = wid & 1;     // unit half
  const int b0 = blockIdx.x * 16;

  for (int i = tid; i < 2 * 2 * 16 * 40; i += 512) {
    ((short*)h1buf)[i] = 0;
    ((short*)h2buf)[i] = 0;
  }

  const int lrow = lane & 15;  // A-frag row / C-frag col
  const int lgrp = lane >> 4;  // 0..3
  const int kb = lgrp * 8;
  const int uu = lrow + 16 * uhalf;  // unit owned in elementwise phase
  const int rbase = roleB * 2;       // which C-rows this wave finishes

  // ---- this wave's 4 gate tiles (one per gate), hi/lo bf16 ----
  const float* W = roleB ? (layer ? whh1 : whh0) : (layer ? wih1 : wih0);
  const int ldk = (roleB || layer) ? 32 : 28;
  short8 Wh[4], Wl[4];
#pragma unroll
  for (int tt = 0; tt < 4; ++tt)
    load_wtile(W, ldk, ldk, 2 * tt + uhalf, lane, Wh[tt], Wl[tt]);

  // input-frag LDS source for non-(L1-A) waves
  short(*hin)[2][16][40] = roleB ? (layer ? h2buf : h1buf) : h1buf;
  short(*hwr)[2][16][40] = layer ? h2buf : h1buf;

  float c[2] = {0, 0}, h[2] = {0, 0};

  const bool isL1A = (layer == 0) && (roleB == 0);
  const float* xrow = x + ((size_t)(b0 + lrow)) * T_LEN * D_IN + kb;
  float4 A0 = make_float4(0, 0, 0, 0), A1 = make_float4(0, 0, 0, 0);
  if (isL1A) {
    A0 = *(const float4*)(xrow);
    if (lgrp < 3) A1 = *(const float4*)(xrow + 4);
  }

  __syncthreads();  // LDS zero-init visible

  for (int s = 0; s < T_LEN + 1; ++s) {
    const int p = s & 1, q = p ^ 1;
    const bool active = (layer == 0) ? (s < T_LEN) : (s >= 1);

    f32x4 acc[4];
    if (active) {
      short8 ah, al;
      if (isL1A) {
        // prefetch x(s+1); stays in flight across both barriers
        int tn = (s + 1 < T_LEN) ? s + 1 : s;
        float4 N0 = *(const float4*)(xrow + (size_t)tn * D_IN);
        float4 N1 = make_float4(0, 0, 0, 0);
        if (lgrp < 3) N1 = *(const float4*)(xrow + (size_t)tn * D_IN + 4);
        float xv[8] = {A0.x, A0.y, A0.z, A0.w, A1.x, A1.y, A1.z, A1.w};
#pragma unroll
        for (int i = 0; i < 8; ++i) {
          short hh_, ll_;
          split_bf16(xv[i], hh_, ll_);
          ah[i] = hh_; al[i] = ll_;
        }
        A0 = N0; A1 = N1;
      } else {
        ah = *(const short8*)&hin[q][0][lrow][kb];
        al = *(const short8*)&hin[q][1][lrow][kb];
      }
#pragma unroll
      for (int tt = 0; tt < 4; ++tt) {
        f32x4 a = {0.f, 0.f, 0.f, 0.f};
        a = MFMA(ah, Wh[tt], a);
        a = MFMA(al, Wh[tt], a);
        a = MFMA(ah, Wl[tt], a);
        acc[tt] = a;
      }
      // publish the partner's row-half of our partial gates (lane-aligned)
      int ro = rbase ^ 2;  // A sends rows 2,3 ; B sends rows 0,1
      f32x4 s0 = {acc[0][ro], acc[0][ro + 1], acc[1][ro], acc[1][ro + 1]};
      f32x4 s1 = {acc[2][ro], acc[2][ro + 1], acc[3][ro], acc[3][ro + 1]};
      *(f32x4*)&xch[layer][uhalf][roleB][lane][0] = s0;
      *(f32x4*)&xch[layer][uhalf][roleB][lane][4] = s1;
    }
    lds_barrier();  // BAR1: exchange visible

    if (active) {
      const float* rd = &xch[layer][uhalf][roleB ^ 1][lane][0];
      // complete gates for our 2 cells: own partial (rows rbase..) + partner
      float g0[2], g1[2], g2[2], g3[2];
#pragma unroll
      for (int j = 0; j < 2; ++j) {
        g0[j] = acc[0][rbase + j] + rd[0 + j];
        g1[j] = acc[1][rbase + j] + rd[2 + j];
        g2[j] = acc[2][rbase + j] + rd[4 + j];
        g3[j] = acc[3][rbase + j] + rd[6 + j];
      }
      // batched cell update (14 trans for 2 cells)
      float ei[2], ef[2], eg[2], eo[2];
#pragma unroll
      for (int j = 0; j < 2; ++j) {
        ei[j] = __builtin_amdgcn_exp2f(g0[j] * -K_SIG);
        ef[j] = __builtin_amdgcn_exp2f(g1[j] * -K_SIG);
        eg[j] = __builtin_amdgcn_exp2f(g2[j] * K_TANH);
        eo[j] = __builtin_amdgcn_exp2f(g3[j] * -K_SIG);
      }
      float cn[2];
#pragma unroll
      for (int j = 0; j < 2; ++j) {
        float pig = (1.0f + ei[j]) * (1.0f + eg[j]);
        float num = c[j] * pig + (eg[j] - 1.0f) * (1.0f + ef[j]);
        cn[j] = num * __builtin_amdgcn_rcpf(pig * (1.0f + ef[j]));
      }
      float ec[2];
#pragma unroll
      for (int j = 0; j < 2; ++j)
        ec[j] = __builtin_amdgcn_exp2f(cn[j] * K_TANH);
#pragma unroll
      for (int j = 0; j < 2; ++j) {
        float R2 = __builtin_amdgcn_rcpf((1.0f + eo[j]) * (1.0f + ec[j]));
        c[j] = cn[j];
        h[j] = (ec[j] - 1.0f) * R2;
        short hh_, ll_;
        split_bf16(h[j], hh_, ll_);
        int row = lgrp * 4 + rbase + j;
        hwr[p][0][row][uu] = hh_;
        hwr[p][1][row][uu] = ll_;
      }
    }
    lds_barrier();  // BAR2: h(s) published
    // Hazards: iter s reads h-parity q pre-BAR1, writes parity p pre-BAR2;
    // iter s+1 writes parity q only after its BAR1 (>= one barrier after all
    // iter-s reads). xch slot written pre-BAR1(s), read before BAR2(s),
    // rewritten only after BAR2(s). All ordered; x prefetch never drained.
  }

  // ---- epilogue: out = h2(T-1) @ wout^T + bout ----
  if (layer == 1) {
#pragma unroll
    for (int j = 0; j < 2; ++j) hf[lgrp * 4 + rbase + j][uu] = h[j];
  }
  __syncthreads();

  for (int j = tid; j < 160; j += 512) {
    int row = j / 10, col = j % 10;
    float s = bout[col];
#pragma unroll
    for (int u = 0; u < 32; ++u) s += hf[row][u] * wout[col * 32 + u];
    out[(size_t)(b0 + row) * 10 + col] = s;
  }
}

extern "C" void kernel_launch(void* const* d_in, const int* in_sizes, int n_in,
                              void* d_out, int out_size, void* d_ws, size_t ws_size,
                              hipStream_t stream) {
  const float* x = (const float*)d_in[0];
  const float* wih0 = (const float*)d_in[1];
  const float* whh0 = (const float*)d_in[2];
  const float* wih1 = (const float*)d_in[3];
  const float* whh1 = (const float*)d_in[4];
  const float* wout = (const float*)d_in[5];
  const float* bout = (const float*)d_in[6];
  float* out = (float*)d_out;
  lstm2_ws<<<256, 512, 0, stream>>>(x, wih0, whh0, wih1, whh1, wout, bout, out);
}

// Round 6
// 475.109 us; speedup vs baseline: 1.1280x; 1.1280x over previous
//
#include <hip/hip_runtime.h>
#include <hip/hip_bf16.h>

// Fused 2-layer LSTM (H=32) + linear head, MI355X gfx950.
// r4 skeleton: 256 WGs x 4 waves, 16 batch rows/WG; waves 0-1 = L1 @ s,
// waves 2-3 = L2 @ s-1; ONE lgkm-only barrier per step.
// r6 changes: (1) MFMA chains interleaved round-major (same-acc distance 4
// => no dependent-MFMA stall at 1 wave/SIMD); (2) x hi/lo split via
// v_perm_b32 packing (24 VALU ops vs ~45); (3) LDS h-reads issued first so
// ds_read latency hides under x-split + x-side MFMA rounds.
// Gates via mfma_f32_16x16x32_bf16 with hi/lo bf16 split (~fp32 exact).

#define T_LEN 512
#define D_IN  28

typedef __attribute__((ext_vector_type(8))) short short8;   // 8 x bf16
typedef __attribute__((ext_vector_type(4))) float f32x4;
typedef __attribute__((ext_vector_type(4))) unsigned int u32x4;

#define K_SIG 1.4426950408889634f   // 1/ln2
#define K_TANH 2.8853900817779268f  // 2/ln2

// hi = bf16 truncation of x, lo = bf16 of exact residual (x - hi).
__device__ __forceinline__ void split_bf16(float x, short& hi, short& lo) {
  unsigned u = __float_as_uint(x);
  hi = (short)(u >> 16);
  float hf_ = __uint_as_float(u & 0xFFFF0000u);
  float lf = x - hf_;  // exact
  lo = (short)(__float_as_uint(lf) >> 16);
}

// dword = (top16(f1) << 16) | top16(f0), one v_perm_b32.
__device__ __forceinline__ unsigned pk_hi16(float f1, float f0) {
  return __builtin_amdgcn_perm(__float_as_uint(f1), __float_as_uint(f0),
                               0x07060302u);
}
__device__ __forceinline__ float trunc_bf(float f) {
  return __uint_as_float(__float_as_uint(f) & 0xFFFF0000u);
}

// Barrier that drains LDS ops only (x prefetch stays in flight).
__device__ __forceinline__ void lds_barrier() {
  asm volatile("s_waitcnt lgkmcnt(0)\n\ts_barrier" ::: "memory");
}

// B-operand tile (K=32 x N=16) of W (row-major G x ldk), gate rows
// n*16..n*16+15, k zero-padded past kval. Lane l: col=l&15, k=(l>>4)*8..+8.
__device__ __forceinline__ void load_wtile(const float* __restrict__ W, int ldk,
                                           int kval, int n, int lane,
                                           short8& hi, short8& lo) {
  int row = n * 16 + (lane & 15);
  int kb = (lane >> 4) * 8;
  const float* p = W + row * ldk + kb;
#pragma unroll
  for (int i = 0; i < 8; ++i) {
    float v = (kb + i < kval) ? p[i] : 0.0f;
    short h, l;
    split_bf16(v, h, l);
    hi[i] = h; lo[i] = l;
  }
}

#define MFMA(a, b, c) __builtin_amdgcn_mfma_f32_16x16x32_bf16(a, b, c, 0, 0, 0)

// Batched LSTM cell update for 4 C-rows. acc[tt][r] = gate (tt: i,f,g,o).
__device__ __forceinline__ void cell_update(const f32x4* acc, float* c, float* h) {
  float ei[4], ef[4], eg[4], eo[4];
#pragma unroll
  for (int r = 0; r < 4; ++r) {
    ei[r] = __builtin_amdgcn_exp2f(acc[0][r] * -K_SIG);
    ef[r] = __builtin_amdgcn_exp2f(acc[1][r] * -K_SIG);
    eg[r] = __builtin_amdgcn_exp2f(acc[2][r] * K_TANH);
    eo[r] = __builtin_amdgcn_exp2f(acc[3][r] * -K_SIG);
  }
  float cn[4];
#pragma unroll
  for (int r = 0; r < 4; ++r) {
    float pig = (1.0f + ei[r]) * (1.0f + eg[r]);
    float num = c[r] * pig + (eg[r] - 1.0f) * (1.0f + ef[r]);
    cn[r] = num * __builtin_amdgcn_rcpf(pig * (1.0f + ef[r]));
  }
  float ec[4];
#pragma unroll
  for (int r = 0; r < 4; ++r) ec[r] = __builtin_amdgcn_exp2f(cn[r] * K_TANH);
#pragma unroll
  for (int r = 0; r < 4; ++r) {
    float R2 = __builtin_amdgcn_rcpf((1.0f + eo[r]) * (1.0f + ec[r]));
    c[r] = cn[r];
    h[r] = (ec[r] - 1.0f) * R2;
  }
}

__global__ __launch_bounds__(256) void lstm2_pipe(
    const float* __restrict__ x, const float* __restrict__ wih0,
    const float* __restrict__ whh0, const float* __restrict__ wih1,
    const float* __restrict__ whh1, const float* __restrict__ wout,
    const float* __restrict__ bout, float* __restrict__ out) {
  __shared__ short h1buf[2][2][16][40];  // [parity][hi/lo][row][unit pad 40]
  __shared__ short h2buf[2][2][16][40];
  __shared__ float hf[16][33];

  const int tid = threadIdx.x;
  const int lane = tid & 63;
  const int wid = tid >> 6;    // 0..3
  const int layer = wid >> 1;  // 0 => L1 waves, 1 => L2 waves
  const int w01 = wid & 1;     // unit-half within the layer
  const int b0 = blockIdx.x * 16;

  for (int i = tid; i < 2 * 2 * 16 * 40; i += 256) {
    ((short*)h1buf)[i] = 0;
    ((short*)h2buf)[i] = 0;
  }

  const int lrow = lane & 15;  // A-frag row / C-frag col
  const int lgrp = lane >> 4;  // 0..3
  const int kb = lgrp * 8;
  const int uu = lrow + 16 * w01;  // unit owned in elementwise phase

  // ---- this wave's layer weights in VGPRs (hi/lo bf16) ----
  const float* Wih = layer ? wih1 : wih0;
  const float* Whh = layer ? whh1 : whh0;
  const int ldk = layer ? 32 : 28;

  short8 Wxh[4], Wxl[4], Whh_[4], Whl[4];
#pragma unroll
  for (int tt = 0; tt < 4; ++tt) {
    int n = tt * 2 + w01;
    load_wtile(Wih, ldk, ldk, n, lane, Wxh[tt], Wxl[tt]);
    load_wtile(Whh, 32, 32, n, lane, Whh_[tt], Whl[tt]);
  }

  float c[4] = {0, 0, 0, 0}, h[4] = {0, 0, 0, 0};

  const float* xrow = x + ((size_t)(b0 + lrow)) * T_LEN * D_IN + kb;
  float4 A0 = make_float4(0, 0, 0, 0), A1 = make_float4(0, 0, 0, 0);
  if (layer == 0) {
    A0 = *(const float4*)(xrow);
    if (lgrp < 3) A1 = *(const float4*)(xrow + 4);
  }

  __syncthreads();  // LDS zero-init visible

  for (int s = 0; s < T_LEN + 1; ++s) {
    const int p = s & 1, q = p ^ 1;
    if (layer == 0) {
      if (s < T_LEN) {
        // LDS h-reads FIRST: latency hides under x work + x-side MFMAs
        short8 ph = *(const short8*)&h1buf[q][0][lrow][kb];
        short8 pl = *(const short8*)&h1buf[q][1][lrow][kb];

        // prefetch x(s+1) - stays in flight across the lds_barrier
        int tn = (s + 1 < T_LEN) ? s + 1 : s;
        float4 N0 = *(const float4*)(xrow + (size_t)tn * D_IN);
        float4 N1 = make_float4(0, 0, 0, 0);
        if (lgrp < 3) N1 = *(const float4*)(xrow + (size_t)tn * D_IN + 4);

        // x -> hi/lo bf16 A-frags via v_perm packing (24 VALU ops)
        u32x4 xhu, xlu;
        xhu[0] = pk_hi16(A0.y, A0.x);
        xhu[1] = pk_hi16(A0.w, A0.z);
        xhu[2] = pk_hi16(A1.y, A1.x);
        xhu[3] = pk_hi16(A1.w, A1.z);
        float l0 = A0.x - trunc_bf(A0.x), l1 = A0.y - trunc_bf(A0.y);
        float l2 = A0.z - trunc_bf(A0.z), l3 = A0.w - trunc_bf(A0.w);
        float l4 = A1.x - trunc_bf(A1.x), l5 = A1.y - trunc_bf(A1.y);
        float l6 = A1.z - trunc_bf(A1.z), l7 = A1.w - trunc_bf(A1.w);
        xlu[0] = pk_hi16(l1, l0);
        xlu[1] = pk_hi16(l3, l2);
        xlu[2] = pk_hi16(l5, l4);
        xlu[3] = pk_hi16(l7, l6);
        short8 xh = __builtin_bit_cast(short8, xhu);
        short8 xl = __builtin_bit_cast(short8, xlu);

        // MFMA rounds, interleaved across the 4 gate accumulators:
        // same-acc reuse distance = 4 MFMAs => no dependent-issue stall.
        f32x4 acc[4];
#pragma unroll
        for (int tt = 0; tt < 4; ++tt) {
          f32x4 z = {0.f, 0.f, 0.f, 0.f};
          acc[tt] = MFMA(xh, Wxh[tt], z);
        }
#pragma unroll
        for (int tt = 0; tt < 4; ++tt) acc[tt] = MFMA(xl, Wxh[tt], acc[tt]);
#pragma unroll
        for (int tt = 0; tt < 4; ++tt) acc[tt] = MFMA(xh, Wxl[tt], acc[tt]);
#pragma unroll
        for (int tt = 0; tt < 4; ++tt) acc[tt] = MFMA(ph, Whh_[tt], acc[tt]);
#pragma unroll
        for (int tt = 0; tt < 4; ++tt) acc[tt] = MFMA(pl, Whh_[tt], acc[tt]);
#pragma unroll
        for (int tt = 0; tt < 4; ++tt) acc[tt] = MFMA(ph, Whl[tt], acc[tt]);

        cell_update(acc, c, h);
#pragma unroll
        for (int r = 0; r < 4; ++r) {
          short hh_, ll_;
          split_bf16(h[r], hh_, ll_);
          int row = lgrp * 4 + r;
          h1buf[p][0][row][uu] = hh_;
          h1buf[p][1][row][uu] = ll_;
        }
        A0 = N0; A1 = N1;
      }
    } else {
      if (s >= 1) {
        // all 4 LDS reads issued up front
        short8 ah = *(const short8*)&h1buf[q][0][lrow][kb];
        short8 al = *(const short8*)&h1buf[q][1][lrow][kb];
        short8 ph = *(const short8*)&h2buf[q][0][lrow][kb];
        short8 pl = *(const short8*)&h2buf[q][1][lrow][kb];
        f32x4 acc[4];
#pragma unroll
        for (int tt = 0; tt < 4; ++tt) {
          f32x4 z = {0.f, 0.f, 0.f, 0.f};
          acc[tt] = MFMA(ah, Wxh[tt], z);
        }
#pragma unroll
        for (int tt = 0; tt < 4; ++tt) acc[tt] = MFMA(al, Wxh[tt], acc[tt]);
#pragma unroll
        for (int tt = 0; tt < 4; ++tt) acc[tt] = MFMA(ah, Wxl[tt], acc[tt]);
#pragma unroll
        for (int tt = 0; tt < 4; ++tt) acc[tt] = MFMA(ph, Whh_[tt], acc[tt]);
#pragma unroll
        for (int tt = 0; tt < 4; ++tt) acc[tt] = MFMA(pl, Whh_[tt], acc[tt]);
#pragma unroll
        for (int tt = 0; tt < 4; ++tt) acc[tt] = MFMA(ph, Whl[tt], acc[tt]);

        cell_update(acc, c, h);
#pragma unroll
        for (int r = 0; r < 4; ++r) {
          short hh_, ll_;
          split_bf16(h[r], hh_, ll_);
          int row = lgrp * 4 + r;
          h2buf[p][0][row][uu] = hh_;
          h2buf[p][1][row][uu] = ll_;
        }
      }
    }
    lds_barrier();
    // Hazard audit: iter s reads parity q, writes parity p; iter s+1 writes
    // parity q only after this barrier; all iter-s reads completed before
    // their consuming MFMAs, which precede barrier arrival. x prefetch is
    // intentionally NOT drained (consumed next iteration via vmcnt wait).
  }

  // ---- epilogue: out = h2(T-1) @ wout^T + bout ----
  if (layer == 1) {
#pragma unroll
    for (int r = 0; r < 4; ++r) hf[lgrp * 4 + r][uu] = h[r];
  }
  __syncthreads();

  for (int j = tid; j < 160; j += 256) {
    int row = j / 10, col = j % 10;
    float s = bout[col];
#pragma unroll
    for (int u = 0; u < 32; ++u) s += hf[row][u] * wout[col * 32 + u];
    out[(size_t)(b0 + row) * 10 + col] = s;
  }
}

extern "C" void kernel_launch(void* const* d_in, const int* in_sizes, int n_in,
                              void* d_out, int out_size, void* d_ws, size_t ws_size,
                              hipStream_t stream) {
  const float* x = (const float*)d_in[0];
  const float* wih0 = (const float*)d_in[1];
  const float* whh0 = (const float*)d_in[2];
  const float* wih1 = (const float*)d_in[3];
  const float* whh1 = (const float*)d_in[4];
  const float* wout = (const float*)d_in[5];
  const float* bout = (const float*)d_in[6];
  float* out = (float*)d_out;
  lstm2_pipe<<<256, 256, 0, stream>>>(x, wih0, whh0, wih1, whh1, wout, bout, out);
}

// Round 7
// 323.346 us; speedup vs baseline: 1.6574x; 1.4694x over previous
//
#include <hip/hip_runtime.h>
#include <hip/hip_bf16.h>

// Fused 2-layer LSTM (H=32) + linear head, MI355X gfx950.
// r4 skeleton: 256 WGs x 4 waves, 16 batch rows/WG; waves 0-1 = L1 @ s,
// waves 2-3 = L2 @ s-1; one lgkm-only barrier per step.
// r7 change: step loop unrolled x2 with STATIC x-prefetch ring (X0/X1).
// A load issued at step s is consumed at s+2 (2 full steps in flight) and
// there are no cross-iteration register copies, so the compiler's waitcnt
// for x never waits on a young load (r6 had an effective vmcnt(0) stall of
// ~HBM latency per step from the A0=N0 bottom-of-loop copy).
// Unroll-2 also makes LDS parity compile-time (immediate ds offsets).
// Gates via mfma_f32_16x16x32_bf16 with hi/lo bf16 split (~fp32 exact).

#define T_LEN 512
#define D_IN  28

typedef __attribute__((ext_vector_type(8))) short short8;   // 8 x bf16
typedef __attribute__((ext_vector_type(4))) float f32x4;
typedef __attribute__((ext_vector_type(4))) unsigned int u32x4;

#define K_SIG 1.4426950408889634f   // 1/ln2
#define K_TANH 2.8853900817779268f  // 2/ln2

// hi = bf16 truncation of x, lo = bf16 of exact residual (x - hi).
__device__ __forceinline__ void split_bf16(float x, short& hi, short& lo) {
  unsigned u = __float_as_uint(x);
  hi = (short)(u >> 16);
  float hf_ = __uint_as_float(u & 0xFFFF0000u);
  float lf = x - hf_;  // exact
  lo = (short)(__float_as_uint(lf) >> 16);
}

// dword = (top16(f1) << 16) | top16(f0), one v_perm_b32.
__device__ __forceinline__ unsigned pk_hi16(float f1, float f0) {
  return __builtin_amdgcn_perm(__float_as_uint(f1), __float_as_uint(f0),
                               0x07060302u);
}
__device__ __forceinline__ float trunc_bf(float f) {
  return __uint_as_float(__float_as_uint(f) & 0xFFFF0000u);
}

// Barrier that drains LDS ops only (x prefetch stays in flight).
__device__ __forceinline__ void lds_barrier() {
  asm volatile("s_waitcnt lgkmcnt(0)\n\ts_barrier" ::: "memory");
}

// B-operand tile (K=32 x N=16) of W (row-major G x ldk), gate rows
// n*16..n*16+15, k zero-padded past kval. Lane l: col=l&15, k=(l>>4)*8..+8.
__device__ __forceinline__ void load_wtile(const float* __restrict__ W, int ldk,
                                           int kval, int n, int lane,
                                           short8& hi, short8& lo) {
  int row = n * 16 + (lane & 15);
  int kb = (lane >> 4) * 8;
  const float* p = W + row * ldk + kb;
#pragma unroll
  for (int i = 0; i < 8; ++i) {
    float v = (kb + i < kval) ? p[i] : 0.0f;
    short h, l;
    split_bf16(v, h, l);
    hi[i] = h; lo[i] = l;
  }
}

#define MFMA(a, b, c) __builtin_amdgcn_mfma_f32_16x16x32_bf16(a, b, c, 0, 0, 0)

// 24 MFMAs interleaved across the 4 gate accumulators (same-acc reuse
// distance 4 => no dependent-issue stall at 1 wave/SIMD).
__device__ __forceinline__ void gate_mfma(f32x4* acc, short8 ah, short8 al,
                                          const short8* Bh, const short8* Bl,
                                          short8 ch, short8 cl,
                                          const short8* Dh, const short8* Dl) {
#pragma unroll
  for (int tt = 0; tt < 4; ++tt) {
    f32x4 z = {0.f, 0.f, 0.f, 0.f};
    acc[tt] = MFMA(ah, Bh[tt], z);
  }
#pragma unroll
  for (int tt = 0; tt < 4; ++tt) acc[tt] = MFMA(al, Bh[tt], acc[tt]);
#pragma unroll
  for (int tt = 0; tt < 4; ++tt) acc[tt] = MFMA(ah, Bl[tt], acc[tt]);
#pragma unroll
  for (int tt = 0; tt < 4; ++tt) acc[tt] = MFMA(ch, Dh[tt], acc[tt]);
#pragma unroll
  for (int tt = 0; tt < 4; ++tt) acc[tt] = MFMA(cl, Dh[tt], acc[tt]);
#pragma unroll
  for (int tt = 0; tt < 4; ++tt) acc[tt] = MFMA(ch, Dl[tt], acc[tt]);
}

// Batched LSTM cell update for 4 C-rows. acc[tt][r] = gate (tt: i,f,g,o).
__device__ __forceinline__ void cell_update(const f32x4* acc, float* c, float* h) {
  float ei[4], ef[4], eg[4], eo[4];
#pragma unroll
  for (int r = 0; r < 4; ++r) {
    ei[r] = __builtin_amdgcn_exp2f(acc[0][r] * -K_SIG);
    ef[r] = __builtin_amdgcn_exp2f(acc[1][r] * -K_SIG);
    eg[r] = __builtin_amdgcn_exp2f(acc[2][r] * K_TANH);
    eo[r] = __builtin_amdgcn_exp2f(acc[3][r] * -K_SIG);
  }
  float cn[4];
#pragma unroll
  for (int r = 0; r < 4; ++r) {
    float pig = (1.0f + ei[r]) * (1.0f + eg[r]);
    float num = c[r] * pig + (eg[r] - 1.0f) * (1.0f + ef[r]);
    cn[r] = num * __builtin_amdgcn_rcpf(pig * (1.0f + ef[r]));
  }
  float ec[4];
#pragma unroll
  for (int r = 0; r < 4; ++r) ec[r] = __builtin_amdgcn_exp2f(cn[r] * K_TANH);
#pragma unroll
  for (int r = 0; r < 4; ++r) {
    float R2 = __builtin_amdgcn_rcpf((1.0f + eo[r]) * (1.0f + ec[r]));
    c[r] = cn[r];
    h[r] = (ec[r] - 1.0f) * R2;
  }
}

// One L1 step at compile-time write-parity P. Consumes (A0,A1) = x(s),
// refills them from ld (= x(min(s+2,511))), which stays in flight 2 steps.
template <int P>
__device__ __forceinline__ void l1_half(
    float4& A0, float4& A1, const float* __restrict__ ld,
    const short8* Wxh, const short8* Wxl, const short8* Whh_, const short8* Whl,
    short (*h1)[2][16][40], float* c, float* h,
    int lrow, int lgrp, int kb, int uu) {
  constexpr int Q = P ^ 1;
  short8 ph = *(const short8*)&h1[Q][0][lrow][kb];
  short8 pl = *(const short8*)&h1[Q][1][lrow][kb];

  // current x -> hi/lo bf16 A-frags (v_perm packing)
  u32x4 xhu, xlu;
  xhu[0] = pk_hi16(A0.y, A0.x);
  xhu[1] = pk_hi16(A0.w, A0.z);
  xhu[2] = pk_hi16(A1.y, A1.x);
  xhu[3] = pk_hi16(A1.w, A1.z);
  float l0 = A0.x - trunc_bf(A0.x), l1 = A0.y - trunc_bf(A0.y);
  float l2 = A0.z - trunc_bf(A0.z), l3 = A0.w - trunc_bf(A0.w);
  float l4 = A1.x - trunc_bf(A1.x), l5 = A1.y - trunc_bf(A1.y);
  float l6 = A1.z - trunc_bf(A1.z), l7 = A1.w - trunc_bf(A1.w);
  xlu[0] = pk_hi16(l1, l0);
  xlu[1] = pk_hi16(l3, l2);
  xlu[2] = pk_hi16(l5, l4);
  xlu[3] = pk_hi16(l7, l6);
  short8 xh = __builtin_bit_cast(short8, xhu);
  short8 xl = __builtin_bit_cast(short8, xlu);

  // refill the ring slot for step s+2 (lgrp==3 lanes keep A1 == 0 forever)
  A0 = *(const float4*)(ld);
  if (lgrp < 3) A1 = *(const float4*)(ld + 4);

  f32x4 acc[4];
  gate_mfma(acc, xh, xl, Wxh, Wxl, ph, pl, Whh_, Whl);
  cell_update(acc, c, h);
#pragma unroll
  for (int r = 0; r < 4; ++r) {
    short hh_, ll_;
    split_bf16(h[r], hh_, ll_);
    int row = lgrp * 4 + r;
    h1[P][0][row][uu] = hh_;
    h1[P][1][row][uu] = ll_;
  }
}

// One L2 step at compile-time write-parity P (computes h2 for step P's
// time index; reads h1 and h2 at parity Q). writeout=false for the tail.
template <int P>
__device__ __forceinline__ void l2_half(
    const short8* Wxh, const short8* Wxl, const short8* Whh_, const short8* Whl,
    short (*h1)[2][16][40], short (*h2)[2][16][40], float* c, float* h,
    int lrow, int lgrp, int kb, int uu, bool writeout) {
  constexpr int Q = P ^ 1;
  short8 ah = *(const short8*)&h1[Q][0][lrow][kb];
  short8 al = *(const short8*)&h1[Q][1][lrow][kb];
  short8 ph = *(const short8*)&h2[Q][0][lrow][kb];
  short8 pl = *(const short8*)&h2[Q][1][lrow][kb];
  f32x4 acc[4];
  gate_mfma(acc, ah, al, Wxh, Wxl, ph, pl, Whh_, Whl);
  cell_update(acc, c, h);
  if (writeout) {
#pragma unroll
    for (int r = 0; r < 4; ++r) {
      short hh_, ll_;
      split_bf16(h[r], hh_, ll_);
      int row = lgrp * 4 + r;
      h2[P][0][row][uu] = hh_;
      h2[P][1][row][uu] = ll_;
    }
  }
}

__global__ __launch_bounds__(256) void lstm2_pipe(
    const float* __restrict__ x, const float* __restrict__ wih0,
    const float* __restrict__ whh0, const float* __restrict__ wih1,
    const float* __restrict__ whh1, const float* __restrict__ wout,
    const float* __restrict__ bout, float* __restrict__ out) {
  __shared__ short h1buf[2][2][16][40];  // [parity][hi/lo][row][unit pad 40]
  __shared__ short h2buf[2][2][16][40];
  __shared__ float hf[16][33];

  const int tid = threadIdx.x;
  const int lane = tid & 63;
  const int wid = tid >> 6;    // 0..3
  const int layer = wid >> 1;  // 0 => L1 waves, 1 => L2 waves
  const int w01 = wid & 1;     // unit-half within the layer
  const int b0 = blockIdx.x * 16;

  for (int i = tid; i < 2 * 2 * 16 * 40; i += 256) {
    ((short*)h1buf)[i] = 0;
    ((short*)h2buf)[i] = 0;
  }

  const int lrow = lane & 15;  // A-frag row / C-frag col
  const int lgrp = lane >> 4;  // 0..3
  const int kb = lgrp * 8;
  const int uu = lrow + 16 * w01;  // unit owned in elementwise phase

  // ---- this wave's layer weights in VGPRs (hi/lo bf16) ----
  const float* Wih = layer ? wih1 : wih0;
  const float* Whh = layer ? whh1 : whh0;
  const int ldk = layer ? 32 : 28;

  short8 Wxh[4], Wxl[4], Whh_[4], Whl[4];
#pragma unroll
  for (int tt = 0; tt < 4; ++tt) {
    int n = tt * 2 + w01;
    load_wtile(Wih, ldk, ldk, n, lane, Wxh[tt], Wxl[tt]);
    load_wtile(Whh, 32, 32, n, lane, Whh_[tt], Whl[tt]);
  }

  float c[4] = {0, 0, 0, 0}, h[4] = {0, 0, 0, 0};

  const float* xrow = x + ((size_t)(b0 + lrow)) * T_LEN * D_IN + kb;

  // static 2-deep x ring: X0 = even steps, X1 = odd steps
  float4 X0A0 = make_float4(0, 0, 0, 0), X0A1 = make_float4(0, 0, 0, 0);
  float4 X1A0 = make_float4(0, 0, 0, 0), X1A1 = make_float4(0, 0, 0, 0);
  if (layer == 0) {
    X0A0 = *(const float4*)(xrow);
    if (lgrp < 3) X0A1 = *(const float4*)(xrow + 4);
    X1A0 = *(const float4*)(xrow + D_IN);
    if (lgrp < 3) X1A1 = *(const float4*)(xrow + D_IN + 4);
  }

  __syncthreads();  // LDS zero-init visible

  for (int s = 0; s < T_LEN; s += 2) {
    // ---- half A: step s, parity 0 ----
    {
      int t2 = s + 2 < T_LEN ? s + 2 : T_LEN - 1;
      const float* ld = xrow + (size_t)t2 * D_IN;
      if (layer == 0) {
        l1_half<0>(X0A0, X0A1, ld, Wxh, Wxl, Whh_, Whl, h1buf, c, h,
                   lrow, lgrp, kb, uu);
      } else if (s > 0) {
        l2_half<0>(Wxh, Wxl, Whh_, Whl, h1buf, h2buf, c, h,
                   lrow, lgrp, kb, uu, true);
      }
      lds_barrier();
    }
    // ---- half B: step s+1, parity 1 ----
    {
      int t3 = s + 3 < T_LEN ? s + 3 : T_LEN - 1;
      const float* ld = xrow + (size_t)t3 * D_IN;
      if (layer == 0) {
        l1_half<1>(X1A0, X1A1, ld, Wxh, Wxl, Whh_, Whl, h1buf, c, h,
                   lrow, lgrp, kb, uu);
      } else {
        l2_half<1>(Wxh, Wxl, Whh_, Whl, h1buf, h2buf, c, h,
                   lrow, lgrp, kb, uu, true);
      }
      lds_barrier();
    }
    // Hazards: step s reads parity q=(s&1)^1, writes p=s&1; step s+1's
    // writes to q are ordered after this step's reads by the barrier.
    // x loads intentionally cross barriers (consumed 2 steps later).
  }

  // ---- tail: step 512, parity 0 — L2 computes h2(511), kept in regs ----
  if (layer == 1) {
    l2_half<0>(Wxh, Wxl, Whh_, Whl, h1buf, h2buf, c, h,
               lrow, lgrp, kb, uu, false);
#pragma unroll
    for (int r = 0; r < 4; ++r) hf[lgrp * 4 + r][uu] = h[r];
  }
  __syncthreads();

  // ---- epilogue: out = h2(T-1) @ wout^T + bout ----
  for (int j = tid; j < 160; j += 256) {
    int row = j / 10, col = j % 10;
    float s = bout[col];
#pragma unroll
    for (int u = 0; u < 32; ++u) s += hf[row][u] * wout[col * 32 + u];
    out[(size_t)(b0 + row) * 10 + col] = s;
  }
}

extern "C" void kernel_launch(void* const* d_in, const int* in_sizes, int n_in,
                              void* d_out, int out_size, void* d_ws, size_t ws_size,
                              hipStream_t stream) {
  const float* x = (const float*)d_in[0];
  const float* wih0 = (const float*)d_in[1];
  const float* whh0 = (const float*)d_in[2];
  const float* wih1 = (const float*)d_in[3];
  const float* whh1 = (const float*)d_in[4];
  const float* wout = (const float*)d_in[5];
  const float* bout = (const float*)d_in[6];
  float* out = (float*)d_out;
  lstm2_pipe<<<256, 256, 0, stream>>>(x, wih0, whh0, wih1, whh1, wout, bout, out);
}